// Round 4
// baseline (240.279 us; speedup 1.0000x reference)
//
#include <hip/hip_runtime.h>
#include <hip/hip_bf16.h>
#include <math.h>

#define B_ 2
#define H_ 12
#define S_ 1024
#define D_ 128
#define TQ 32
#define TK 32
#define NW 4
#define SCALE 0.08838834764831843f

#define QROWS (S_ + 16)            /* 1040 */
#define KROWS (16 + S_ + 16)       /* 1056 */

#define QBLK 3120                  /* 24*1040*128/4/256 */
#define KBLK 3168                  /* 24*1056*128/4/256 */
#define VBLK 3072                  /* 24*32*4 transpose tiles */

typedef __attribute__((ext_vector_type(8))) short short8;
typedef __attribute__((ext_vector_type(4))) float floatx4;

__device__ __forceinline__ unsigned short f2b(float f) {
    return __builtin_bit_cast(unsigned short, __float2bfloat16(f));
}

// ---- fused prepass: Q/K f32->bf16 padded, V -> V^T bf16 --------------------
__global__ __launch_bounds__(256) void prep_kernel(
    const float* __restrict__ Q, const float* __restrict__ K,
    const float* __restrict__ V,
    unsigned short* __restrict__ Qp, unsigned short* __restrict__ Kp,
    unsigned short* __restrict__ Vt)
{
    __shared__ float ls[32][33];
    const int bid = blockIdx.x;
    const int tid = threadIdx.x;
    if (bid < QBLK) {
        int e0 = (bid * 256 + tid) * 4;
        int bh = e0 / (QROWS * D_);
        int rem = e0 - bh * (QROWS * D_);
        int r = rem >> 7, d = rem & 127;
        int sr = r - 16;
        float4 v = make_float4(0.f, 0.f, 0.f, 0.f);
        if (sr >= 0 && sr < S_) v = *(const float4*)(Q + ((size_t)bh * S_ + sr) * D_ + d);
        ushort4 o; o.x = f2b(v.x); o.y = f2b(v.y); o.z = f2b(v.z); o.w = f2b(v.w);
        *(ushort4*)(Qp + ((size_t)bh * QROWS + r) * D_ + d) = o;
    } else if (bid < QBLK + KBLK) {
        int e0 = ((bid - QBLK) * 256 + tid) * 4;
        int bh = e0 / (KROWS * D_);
        int rem = e0 - bh * (KROWS * D_);
        int r = rem >> 7, d = rem & 127;
        int sr = r - 16;
        float4 v = make_float4(0.f, 0.f, 0.f, 0.f);
        if (sr >= 0 && sr < S_) v = *(const float4*)(K + ((size_t)bh * S_ + sr) * D_ + d);
        ushort4 o; o.x = f2b(v.x); o.y = f2b(v.y); o.z = f2b(v.z); o.w = f2b(v.w);
        *(ushort4*)(Kp + ((size_t)bh * KROWS + r) * D_ + d) = o;
    } else {
        int b = bid - (QBLK + KBLK);
        int dt = b & 3; int kt = (b >> 2) & 31; int bh = b >> 7;
        int lk = tid >> 3, ld = (tid & 7) * 4;
        float4 v = *(const float4*)(V + ((size_t)bh * S_ + kt * 32 + lk) * D_ + dt * 32 + ld);
        ls[lk][ld + 0] = v.x; ls[lk][ld + 1] = v.y; ls[lk][ld + 2] = v.z; ls[lk][ld + 3] = v.w;
        __syncthreads();
        int lk2 = tid >> 3, lc = (tid & 7) * 4;
        ushort4 o;
        o.x = f2b(ls[lc + 0][lk2]); o.y = f2b(ls[lc + 1][lk2]);
        o.z = f2b(ls[lc + 2][lk2]); o.w = f2b(ls[lc + 3][lk2]);
        *(ushort4*)(Vt + ((size_t)bh * D_ + dt * 32 + lk2) * S_ + kt * 32 + lc) = o;
    }
}

// ---- main fused kernel ------------------------------------------------------
__global__ __launch_bounds__(256, 2) void conv_attn_mfma(
    const unsigned short* __restrict__ Qp,  // [24][1040][128] bf16
    const unsigned short* __restrict__ Kp,  // [24][1056][128] bf16
    const unsigned short* __restrict__ Vt,  // [24][128][1024] bf16
    const float* __restrict__ W,            // [12][6][11]
    float* __restrict__ O)                  // [24][1024][128] f32
{
    __shared__ __align__(16) unsigned short Qs[48][136];   // 13056 B
    __shared__ __align__(16) union {
        float sc[NW][48][52];               // 39936 B, per-wave f32 score tiles
        float oacc[32][132];                // 16896 B, merge buffer
    } u;
    __shared__ float m_all[NW][32], l_all[NW][32], ms_s[32], inv_s[32];

    const int tid = threadIdx.x;
    const int wv = tid >> 6;
    const int ln = tid & 63;
    const int l15 = ln & 15;
    const int qd = ln >> 4;

    const int bid = blockIdx.x;
    const int bh = bid % (B_ * H_);
    const int qt = (S_ / TQ - 1) - bid / (B_ * H_);   // heavy tiles first
    const int h = bh % H_;
    const int q0 = qt * TQ;

    const unsigned short* Qb = Qp + (size_t)bh * QROWS * D_;
    const unsigned short* Kb = Kp + (size_t)bh * KROWS * D_;
    const unsigned short* Vb = Vt + (size_t)bh * D_ * S_;
    const float* Wh = W + h * 66;

    // stage Q tile (padded rows q0 .. q0+47) into LDS
    for (int idx = tid; idx < 48 * 16; idx += 256) {
        int r = idx >> 4, c8 = (idx & 15) * 8;
        *(short8*)&Qs[r][c8] = *(const short8*)(Qb + (size_t)(q0 + r) * D_ + c8);
    }
    __syncthreads();

    floatx4 acc[2][8];
    #pragma unroll
    for (int mt = 0; mt < 2; ++mt)
        #pragma unroll
        for (int nt = 0; nt < 8; ++nt)
            acc[mt][nt] = (floatx4){0.f, 0.f, 0.f, 0.f};
    float m_run[2] = {-INFINITY, -INFINITY};
    float l_run[2] = {0.f, 0.f};

    const int nkt = qt + 1;
    for (int kt = wv; kt < nkt; kt += NW) {
        const int k0 = kt * TK;

        // ---- scores: 48x48 tile via MFMA, masked, f32 -> LDS ---------------
        // kf[4] held; qf fragments reloaded from LDS per MFMA (low pressure)
        #pragma unroll
        for (int nt = 0; nt < 3; ++nt) {
            const unsigned short* krow = Kb + (size_t)(k0 + 8 + nt * 16 + l15) * D_;
            short8 kf[4];
            #pragma unroll
            for (int kc = 0; kc < 4; ++kc)
                kf[kc] = *(const short8*)(krow + kc * 32 + qd * 8);
            #pragma unroll
            for (int mt = 0; mt < 3; ++mt) {
                floatx4 s = {0.f, 0.f, 0.f, 0.f};
                #pragma unroll
                for (int kc = 0; kc < 4; ++kc) {
                    short8 qf = *(const short8*)&Qs[mt * 16 + l15][kc * 32 + qd * 8];
                    s = __builtin_amdgcn_mfma_f32_16x16x32_bf16(qf, kf[kc], s, 0, 0, 0);
                }
                const int qrow = q0 - 16 + mt * 16 + qd * 4;
                const int kcol = k0 - 8 + nt * 16 + l15;
                #pragma unroll
                for (int reg = 0; reg < 4; ++reg)
                    u.sc[wv][mt * 16 + qd * 4 + reg][nt * 16 + l15] =
                        (kcol <= qrow + reg) ? s[reg] : 0.f;
            }
        }

        // ---- V fragments issued here: conv VALU below hides the latency ----
        short8 vf[8];
        #pragma unroll
        for (int nt = 0; nt < 8; ++nt)
            vf[nt] = *(const short8*)(Vb + (size_t)(nt * 16 + l15) * S_ + k0 + qd * 8);

        // ---- 6x11 conv on VALU, f32 scores from LDS ------------------------
        float pl[2][8];
        #pragma unroll
        for (int mt2 = 0; mt2 < 2; ++mt2)
            #pragma unroll
            for (int jj = 0; jj < 8; ++jj) pl[mt2][jj] = 0.f;
        #pragma unroll
        for (int mt2 = 0; mt2 < 2; ++mt2) {
            #pragma unroll
            for (int i = 0; i < 6; ++i) {
                const float* rp = &u.sc[wv][l15 + 11 + 16 * mt2 + i][qd * 8];
                float4 a0 = ((const float4*)rp)[0];
                float4 a1 = ((const float4*)rp)[1];
                float4 a2 = ((const float4*)rp)[2];
                float4 a3 = ((const float4*)rp)[3];
                float4 a4 = ((const float4*)rp)[4];
                float2 a5 = *(const float2*)(rp + 20);
                float win[22] = {a0.x, a0.y, a0.z, a0.w, a1.x, a1.y, a1.z, a1.w,
                                 a2.x, a2.y, a2.z, a2.w, a3.x, a3.y, a3.z, a3.w,
                                 a4.x, a4.y, a4.z, a4.w, a5.x, a5.y};
                #pragma unroll
                for (int j = 0; j < 11; ++j) {
                    const float w = Wh[i * 11 + j];   // uniform -> SGPR
                    #pragma unroll
                    for (int jj = 0; jj < 8; ++jj)
                        pl[mt2][jj] = fmaf(w, win[3 + j + jj], pl[mt2][jj]);
                }
            }
        }

        // ---- online softmax (per wave, rows split across quads) ------------
        float al[2];
        short8 pfrag[2];
        #pragma unroll
        for (int mt2 = 0; mt2 < 2; ++mt2) {
            const int qrow = q0 + l15 + 16 * mt2;
            float lg[8];
            float mx = -1e30f;
            #pragma unroll
            for (int jj = 0; jj < 8; ++jj) {
                const int kcol = k0 + qd * 8 + jj;
                lg[jj] = (kcol <= qrow) ? pl[mt2][jj] * SCALE : -1e30f;
                mx = fmaxf(mx, lg[jj]);
            }
            mx = fmaxf(mx, __shfl_xor(mx, 16));
            mx = fmaxf(mx, __shfl_xor(mx, 32));
            const float nm = fmaxf(m_run[mt2], mx);
            al[mt2] = __expf(m_run[mt2] - nm);
            float sum = 0.f;
            short8 pb;
            #pragma unroll
            for (int jj = 0; jj < 8; ++jj) {
                float p = __expf(lg[jj] - nm);
                sum += p;
                pb[jj] = (short)f2b(p);
            }
            sum += __shfl_xor(sum, 16);
            sum += __shfl_xor(sum, 32);
            l_run[mt2] = l_run[mt2] * al[mt2] + sum;
            m_run[mt2] = nm;
            pfrag[mt2] = pb;
        }

        // rescale accumulator
        #pragma unroll
        for (int mt = 0; mt < 2; ++mt) {
            #pragma unroll
            for (int reg = 0; reg < 4; ++reg) {
                const float af = __shfl(al[mt], qd * 4 + reg, 64);
                #pragma unroll
                for (int nt = 0; nt < 8; ++nt)
                    acc[mt][nt][reg] *= af;
            }
        }

        // ---- P @ V via MFMA -------------------------------------------------
        #pragma unroll
        for (int nt = 0; nt < 8; ++nt)
            #pragma unroll
            for (int mt = 0; mt < 2; ++mt)
                acc[mt][nt] = __builtin_amdgcn_mfma_f32_16x16x32_bf16(pfrag[mt], vf[nt], acc[mt][nt], 0, 0, 0);
    }

    // ---- merge the 4 waves' partials ---------------------------------------
    if (qd == 0) {
        m_all[wv][l15] = m_run[0]; m_all[wv][l15 + 16] = m_run[1];
        l_all[wv][l15] = l_run[0]; l_all[wv][l15 + 16] = l_run[1];
    }
    __syncthreads();
    if (tid < 32) {
        float ms = -INFINITY;
        #pragma unroll
        for (int w = 0; w < NW; ++w) ms = fmaxf(ms, m_all[w][tid]);
        float ls = 0.f;
        #pragma unroll
        for (int w = 0; w < NW; ++w) ls += __expf(m_all[w][tid] - ms) * l_all[w][tid];
        ms_s[tid] = ms;
        inv_s[tid] = 1.f / ls;
    }
    __syncthreads();
    for (int w = 0; w < NW; ++w) {
        if (wv == w) {
            #pragma unroll
            for (int mt = 0; mt < 2; ++mt) {
                #pragma unroll
                for (int reg = 0; reg < 4; ++reg) {
                    const int row = mt * 16 + qd * 4 + reg;
                    const float f = __expf(m_all[wv][row] - ms_s[row]);
                    #pragma unroll
                    for (int nt = 0; nt < 8; ++nt) {
                        const float val = acc[mt][nt][reg] * f;
                        if (w == 0) u.oacc[row][nt * 16 + l15] = val;
                        else        u.oacc[row][nt * 16 + l15] += val;
                    }
                }
            }
        }
        __syncthreads();
    }

    // ---- normalize + store --------------------------------------------------
    {
        const int r = tid >> 3;
        const int c0 = (tid & 7) * 16;
        const float inv = inv_s[r];
        float* orow = O + ((size_t)bh * S_ + q0 + r) * D_ + c0;
        #pragma unroll
        for (int g = 0; g < 4; ++g) {
            float4 o;
            o.x = u.oacc[r][c0 + g * 4 + 0] * inv;
            o.y = u.oacc[r][c0 + g * 4 + 1] * inv;
            o.z = u.oacc[r][c0 + g * 4 + 2] * inv;
            o.w = u.oacc[r][c0 + g * 4 + 3] * inv;
            *(float4*)(orow + g * 4) = o;
        }
    }
}

extern "C" void kernel_launch(void* const* d_in, const int* in_sizes, int n_in,
                              void* d_out, int out_size, void* d_ws, size_t ws_size,
                              hipStream_t stream) {
    const float* Q = (const float*)d_in[0];
    const float* K = (const float*)d_in[1];
    const float* V = (const float*)d_in[2];
    const float* W = (const float*)d_in[3];
    float* O = (float*)d_out;

    unsigned short* Qp = (unsigned short*)d_ws;                        // 6389760 B
    unsigned short* Kp = (unsigned short*)((char*)d_ws + 6389760);     // 6488064 B
    unsigned short* Vt = (unsigned short*)((char*)d_ws + 12877824);    // 6291456 B

    prep_kernel<<<dim3(QBLK + KBLK + VBLK), dim3(256), 0, stream>>>(Q, K, V, Qp, Kp, Vt);
    conv_attn_mfma<<<dim3(B_ * H_ * (S_ / TQ)), dim3(256), 0, stream>>>(Qp, Kp, Vt, W, O);
}

// Round 5
// 233.648 us; speedup vs baseline: 1.0284x; 1.0284x over previous
//
#include <hip/hip_runtime.h>
#include <hip/hip_bf16.h>
#include <math.h>

#define B_ 2
#define H_ 12
#define S_ 1024
#define D_ 128
#define TQ 64
#define TK 32
#define SCALE 0.08838834764831843f

#define QROWS (S_ + 16)            /* 1040 */
#define KROWS (16 + S_ + 16)       /* 1056 */

#define QBLK 3120                  /* 24*1040*128/4/256 */
#define KBLK 3168                  /* 24*1056*128/4/256 */
#define VBLK 3072                  /* 24*32*4 transpose tiles */

typedef __attribute__((ext_vector_type(8))) short short8;
typedef __attribute__((ext_vector_type(4))) float floatx4;

__device__ __forceinline__ unsigned short f2b(float f) {
    return __builtin_bit_cast(unsigned short, __float2bfloat16(f));
}

// ---- fused prepass: Q/K f32->bf16 padded, V -> V^T bf16 --------------------
__global__ __launch_bounds__(256) void prep_kernel(
    const float* __restrict__ Q, const float* __restrict__ K,
    const float* __restrict__ V,
    unsigned short* __restrict__ Qp, unsigned short* __restrict__ Kp,
    unsigned short* __restrict__ Vt)
{
    __shared__ float ls[32][33];
    const int bid = blockIdx.x;
    const int tid = threadIdx.x;
    if (bid < QBLK) {
        int e0 = (bid * 256 + tid) * 4;
        int bh = e0 / (QROWS * D_);
        int rem = e0 - bh * (QROWS * D_);
        int r = rem >> 7, d = rem & 127;
        int sr = r - 16;
        float4 v = make_float4(0.f, 0.f, 0.f, 0.f);
        if (sr >= 0 && sr < S_) v = *(const float4*)(Q + ((size_t)bh * S_ + sr) * D_ + d);
        ushort4 o; o.x = f2b(v.x); o.y = f2b(v.y); o.z = f2b(v.z); o.w = f2b(v.w);
        *(ushort4*)(Qp + ((size_t)bh * QROWS + r) * D_ + d) = o;
    } else if (bid < QBLK + KBLK) {
        int e0 = ((bid - QBLK) * 256 + tid) * 4;
        int bh = e0 / (KROWS * D_);
        int rem = e0 - bh * (KROWS * D_);
        int r = rem >> 7, d = rem & 127;
        int sr = r - 16;
        float4 v = make_float4(0.f, 0.f, 0.f, 0.f);
        if (sr >= 0 && sr < S_) v = *(const float4*)(K + ((size_t)bh * S_ + sr) * D_ + d);
        ushort4 o; o.x = f2b(v.x); o.y = f2b(v.y); o.z = f2b(v.z); o.w = f2b(v.w);
        *(ushort4*)(Kp + ((size_t)bh * KROWS + r) * D_ + d) = o;
    } else {
        int b = bid - (QBLK + KBLK);
        int dt = b & 3; int kt = (b >> 2) & 31; int bh = b >> 7;
        int lk = tid >> 3, ld = (tid & 7) * 4;
        float4 v = *(const float4*)(V + ((size_t)bh * S_ + kt * 32 + lk) * D_ + dt * 32 + ld);
        ls[lk][ld + 0] = v.x; ls[lk][ld + 1] = v.y; ls[lk][ld + 2] = v.z; ls[lk][ld + 3] = v.w;
        __syncthreads();
        int lk2 = tid >> 3, lc = (tid & 7) * 4;
        ushort4 o;
        o.x = f2b(ls[lc + 0][lk2]); o.y = f2b(ls[lc + 1][lk2]);
        o.z = f2b(ls[lc + 2][lk2]); o.w = f2b(ls[lc + 3][lk2]);
        *(ushort4*)(Vt + ((size_t)bh * D_ + dt * 32 + lk2) * S_ + kt * 32 + lc) = o;
    }
}

// ---- main fused kernel: 4 waves cooperate on one k-tile ---------------------
__global__ __launch_bounds__(256, 2) void conv_attn_mfma(
    const unsigned short* __restrict__ Qp,  // [24][1040][128] bf16
    const unsigned short* __restrict__ Kp,  // [24][1056][128] bf16
    const unsigned short* __restrict__ Vt,  // [24][128][1024] bf16
    const float* __restrict__ W,            // [12][6][11]
    float* __restrict__ O)                  // [24][1024][128] f32
{
    __shared__ __align__(16) unsigned short Qs[80][136];  // 21760 B
    __shared__ __align__(16) float sc[80][52];            // 16640 B
    __shared__ __align__(16) unsigned short P[2][64][40]; // 10240 B (dbuf)
    __shared__ __align__(16) float al_s[2][64];           //   512 B

    const int tid = threadIdx.x;
    const int wv = tid >> 6;
    const int ln = tid & 63;
    const int l15 = ln & 15;
    const int qd = ln >> 4;

    // XCD-swizzled mapping: XCD x (bid%8) sees only bh in {3x,3x+1,3x+2}
    const int bid = blockIdx.x;
    const int bh = (bid & 7) * 3 + ((bid >> 3) % 3);
    const int qt = 15 - bid / 24;                 // heavy q-tiles dispatched first
    const int h = bh % H_;
    const int q0 = qt * TQ;

    const unsigned short* Qb = Qp + (size_t)bh * QROWS * D_;
    const unsigned short* Kb = Kp + (size_t)bh * KROWS * D_;
    const unsigned short* Vb = Vt + (size_t)bh * D_ * S_;
    const float* Wh = W + h * 66;

    // stage Q rows q0-16 .. q0+63 (Qp is 16-padded: Qp row q0+r)
    for (int idx = tid; idx < 80 * 16; idx += 256) {
        int r = idx >> 4, c8 = (idx & 15) * 8;
        *(short8*)&Qs[r][c8] = *(const short8*)(Qb + (size_t)(q0 + r) * D_ + c8);
    }
    __syncthreads();

    // per-wave score-unit assignment: units u = nt*5+mt, wave w -> u in [4w, 4w+4) ∩ [0,15)
    int nt_t[4], mt_t[4], kro_t[4];
    #pragma unroll
    for (int t = 0; t < 4; ++t) {
        int u = wv * 4 + t;
        int nt = u / 5;
        nt_t[t] = nt; mt_t[t] = u - nt * 5;
        kro_t[t] = 8 + nt * 16 + l15;             // Kp row offset (Kp is 16-padded: +8 = -8 halo)
    }

    // conv-lane geometry: this lane owns conv row p, cols c0..c0+7
    const int p = 16 * wv + (ln >> 2);
    const int c0 = (ln & 3) * 8;

    floatx4 acc[4][2];
    #pragma unroll
    for (int mt = 0; mt < 4; ++mt)
        #pragma unroll
        for (int n2 = 0; n2 < 2; ++n2)
            acc[mt][n2] = (floatx4){0.f, 0.f, 0.f, 0.f};
    float m_run = -INFINITY, l_run = 0.f;

    const int nkt = 2 * qt + 2;
    for (int kt = 0; kt < nkt; ++kt) {
        const int k0 = kt * TK;
        const int par = kt & 1;

        // ---- scores: 80x48 halo tile via MFMA, masked, f32 -> LDS ----------
        #pragma unroll
        for (int t = 0; t < 4; ++t) {
            if (wv * 4 + t < 15) {
                const int nt = nt_t[t], mt = mt_t[t];
                const unsigned short* krow = Kb + (size_t)(k0 + kro_t[t]) * D_;
                short8 kf[4], qf[4];
                #pragma unroll
                for (int kc = 0; kc < 4; ++kc) {
                    kf[kc] = *(const short8*)(krow + kc * 32 + qd * 8);
                    qf[kc] = *(const short8*)&Qs[mt * 16 + l15][kc * 32 + qd * 8];
                }
                floatx4 s = {0.f, 0.f, 0.f, 0.f};
                #pragma unroll
                for (int kc = 0; kc < 4; ++kc)
                    s = __builtin_amdgcn_mfma_f32_16x16x32_bf16(qf[kc], kf[kc], s, 0, 0, 0);
                const int qrow = q0 - 16 + mt * 16 + qd * 4;  // global q of reg 0
                const int kcol = k0 - 8 + nt * 16 + l15;      // global k
                #pragma unroll
                for (int reg = 0; reg < 4; ++reg)
                    sc[mt * 16 + qd * 4 + reg][nt * 16 + l15] =
                        (kcol <= qrow + reg) ? s[reg] : 0.f;
            }
        }
        __syncthreads();   // B1: sc ready

        // ---- 6x11 conv: lane owns (row p, cols c0..c0+7) -------------------
        float pl[8];
        #pragma unroll
        for (int jj = 0; jj < 8; ++jj) pl[jj] = 0.f;
        #pragma unroll
        for (int i = 0; i < 6; ++i) {
            const float* rp = &sc[p + 11 + i][c0];
            float4 b0 = ((const float4*)rp)[0];
            float4 b1 = ((const float4*)rp)[1];
            float4 b2 = ((const float4*)rp)[2];
            float4 b3 = ((const float4*)rp)[3];
            float4 b4 = ((const float4*)rp)[4];
            float4 b5 = ((const float4*)rp)[5];
            float win[24] = {b0.x, b0.y, b0.z, b0.w, b1.x, b1.y, b1.z, b1.w,
                             b2.x, b2.y, b2.z, b2.w, b3.x, b3.y, b3.z, b3.w,
                             b4.x, b4.y, b4.z, b4.w, b5.x, b5.y, b5.z, b5.w};
            #pragma unroll
            for (int j = 0; j < 11; ++j) {
                const float w = Wh[i * 11 + j];   // wave-uniform -> SGPR
                #pragma unroll
                for (int jj = 0; jj < 8; ++jj)
                    pl[jj] = fmaf(w, win[3 + j + jj], pl[jj]);
            }
        }

        // ---- online softmax for row p (4 lanes per row) --------------------
        {
            const int q = q0 + p;
            float lg[8];
            float mx = -1e30f;
            #pragma unroll
            for (int jj = 0; jj < 8; ++jj) {
                const int k = k0 + c0 + jj;
                lg[jj] = (k <= q) ? pl[jj] * SCALE : -1e30f;
                mx = fmaxf(mx, lg[jj]);
            }
            mx = fmaxf(mx, __shfl_xor(mx, 1));
            mx = fmaxf(mx, __shfl_xor(mx, 2));
            const float nm = fmaxf(m_run, mx);
            const float alpha = __expf(m_run - nm);
            float sum = 0.f;
            short8 pb;
            #pragma unroll
            for (int jj = 0; jj < 8; ++jj) {
                float pv = __expf(lg[jj] - nm);
                sum += pv;
                pb[jj] = (short)f2b(pv);
            }
            sum += __shfl_xor(sum, 1);
            sum += __shfl_xor(sum, 2);
            l_run = l_run * alpha + sum;
            m_run = nm;
            *(short8*)&P[par][p][c0] = pb;
            if ((ln & 3) == 0) al_s[par][p] = alpha;
        }
        __syncthreads();   // B2: P/alpha ready; sc consumed

        // ---- rescale + P @ V (wave owns output cols 32*wv .. 32*wv+31) -----
        {
            float4 al4[4];
            #pragma unroll
            for (int mt = 0; mt < 4; ++mt)
                al4[mt] = *(const float4*)&al_s[par][mt * 16 + qd * 4];
            #pragma unroll
            for (int mt = 0; mt < 4; ++mt) {
                #pragma unroll
                for (int n2 = 0; n2 < 2; ++n2) {
                    acc[mt][n2][0] *= al4[mt].x;
                    acc[mt][n2][1] *= al4[mt].y;
                    acc[mt][n2][2] *= al4[mt].z;
                    acc[mt][n2][3] *= al4[mt].w;
                }
            }
            short8 pf[4];
            #pragma unroll
            for (int mt = 0; mt < 4; ++mt)
                pf[mt] = *(const short8*)&P[par][mt * 16 + l15][qd * 8];
            short8 vfr[2];
            #pragma unroll
            for (int n2 = 0; n2 < 2; ++n2) {
                const int d = (2 * wv + n2) * 16 + l15;
                vfr[n2] = *(const short8*)(Vb + (size_t)d * S_ + k0 + qd * 8);
            }
            #pragma unroll
            for (int n2 = 0; n2 < 2; ++n2)
                #pragma unroll
                for (int mt = 0; mt < 4; ++mt)
                    acc[mt][n2] = __builtin_amdgcn_mfma_f32_16x16x32_bf16(pf[mt], vfr[n2], acc[mt][n2], 0, 0, 0);
        }
        // no barrier: next iter's sc writes are safe (sc consumed pre-B2);
        // P/al parity writes are 2 barriers away from these reads
    }

    // ---- epilogue: 1/l per row, normalize, store ---------------------------
    __syncthreads();
    if ((ln & 3) == 0) al_s[0][p] = 1.0f / l_run;
    __syncthreads();
    {
        float4 inv4[4];
        #pragma unroll
        for (int mt = 0; mt < 4; ++mt)
            inv4[mt] = *(const float4*)&al_s[0][mt * 16 + qd * 4];
        float* Ob = O + (size_t)bh * S_ * D_;
        #pragma unroll
        for (int mt = 0; mt < 4; ++mt) {
            const float iv[4] = {inv4[mt].x, inv4[mt].y, inv4[mt].z, inv4[mt].w};
            #pragma unroll
            for (int reg = 0; reg < 4; ++reg) {
                const int row = mt * 16 + qd * 4 + reg;
                #pragma unroll
                for (int n2 = 0; n2 < 2; ++n2) {
                    const int col = (2 * wv + n2) * 16 + l15;
                    Ob[(size_t)(q0 + row) * D_ + col] = acc[mt][n2][reg] * iv[reg];
                }
            }
        }
    }
}

extern "C" void kernel_launch(void* const* d_in, const int* in_sizes, int n_in,
                              void* d_out, int out_size, void* d_ws, size_t ws_size,
                              hipStream_t stream) {
    const float* Q = (const float*)d_in[0];
    const float* K = (const float*)d_in[1];
    const float* V = (const float*)d_in[2];
    const float* W = (const float*)d_in[3];
    float* O = (float*)d_out;

    unsigned short* Qp = (unsigned short*)d_ws;                        // 6389760 B
    unsigned short* Kp = (unsigned short*)((char*)d_ws + 6389760);     // 6488064 B
    unsigned short* Vt = (unsigned short*)((char*)d_ws + 12877824);    // 6291456 B

    prep_kernel<<<dim3(QBLK + KBLK + VBLK), dim3(256), 0, stream>>>(Q, K, V, Qp, Kp, Vt);
    conv_attn_mfma<<<dim3(B_ * H_ * (S_ / TQ)), dim3(256), 0, stream>>>(Qp, Kp, Vt, W, O);
}